// Round 2
// baseline (5129.827 us; speedup 1.0000x reference)
//
#include <hip/hip_runtime.h>
#include <hip/hip_bf16.h>
#include <math.h>

#define BB 4
#define NN 16384
#define KM 128
#define DD 128
#define HHD 8
#define LL 6
#define DFFN 512
#define NFF 16
#define DCC 64
#define MM 257
#define DHH 16
#define SKC 16

// ---------------- embed: bases + h0 ----------------
__global__ void k_embed(const float* __restrict__ u, const float* __restrict__ nodes,
                        const float* __restrict__ modes, const float* __restrict__ coordB,
                        const float* __restrict__ cp_w, const float* __restrict__ cp_b,
                        const float* __restrict__ in_w, const float* __restrict__ in_b,
                        float* __restrict__ bases, float* __restrict__ h) {
  int p = blockIdx.x;          // 0..B*N-1
  int tid = threadIdx.x;       // 128
  float n0 = nodes[(size_t)p * 2 + 0], n1 = nodes[(size_t)p * 2 + 1];
  float tk = n0 * modes[tid * 2 + 0] + n1 * modes[tid * 2 + 1];
  float* bp = bases + (size_t)p * MM;
  bp[tid] = cosf(tk);
  bp[KM + tid] = sinf(tk);
  if (tid == 0) bp[2 * KM] = 1.0f;
  __shared__ float feats[34];
  __shared__ float hin[66];
  if (tid < NFF) {
    float xb = n0 * coordB[tid] + n1 * coordB[NFF + tid];
    feats[2 + tid] = sinf(xb);
    feats[2 + NFF + tid] = cosf(xb);
  }
  if (tid == 0) { feats[0] = n0; feats[1] = n1; hin[0] = u[(size_t)p * 2]; hin[1] = u[(size_t)p * 2 + 1]; }
  __syncthreads();
  if (tid < DCC) {
    float acc = cp_b[tid];
    #pragma unroll
    for (int i = 0; i < 34; i++) acc += feats[i] * cp_w[i * DCC + tid];
    hin[2 + tid] = acc;
  }
  __syncthreads();
  float acc = in_b[tid];
  #pragma unroll
  for (int i = 0; i < 66; i++) acc += hin[i] * in_w[i * DD + tid];
  h[(size_t)p * DD + tid] = acc;
}

// ---------------- slice: partial[b][sk][t][d] = sum_x h*bases*w ----------------
__global__ void k_slice(const float* __restrict__ bases, const float* __restrict__ h,
                        const float* __restrict__ w, float* __restrict__ partial) {
  int sk = blockIdx.x, tt = blockIdx.y, b = blockIdx.z;
  int t0 = tt * 32;
  int nt = MM - t0; if (nt > 32) nt = 32;
  int x0 = sk * (NN / SKC);
  __shared__ float hs[64][128];
  __shared__ float bs[64][32];
  int tid = threadIdx.x;
  int d = tid & 127, g = tid >> 7;
  float acc[16];
  #pragma unroll
  for (int i = 0; i < 16; i++) acc[i] = 0.f;
  for (int xs = 0; xs < NN / SKC; xs += 64) {
    const float* hptr = h + ((size_t)b * NN + x0 + xs) * DD;
    for (int kk = tid; kk < 64 * 128; kk += 256) hs[kk >> 7][kk & 127] = hptr[kk];
    const float* bptr = bases + ((size_t)b * NN + x0 + xs) * MM + t0;
    const float* wptr = w + (size_t)b * NN + x0 + xs;
    for (int kk = tid; kk < 64 * 32; kk += 256) {
      int xl = kk >> 5, tl = kk & 31;
      bs[xl][tl] = (tl < nt) ? bptr[(size_t)xl * MM + tl] * wptr[xl] : 0.f;
    }
    __syncthreads();
    for (int xl = 0; xl < 64; xl++) {
      float hv = hs[xl][d];
      const float* brow = &bs[xl][g * 16];
      #pragma unroll
      for (int i = 0; i < 16; i++) acc[i] += hv * brow[i];
    }
    __syncthreads();
  }
  float* pp = partial + ((size_t)(b * SKC + sk) * MM) * DD;
  #pragma unroll
  for (int i = 0; i < 16; i++) {
    int t = t0 + g * 16 + i;
    if (t < MM) pp[(size_t)t * DD + d] = acc[i];
  }
}

__global__ void k_reduce(const float* __restrict__ partial, float* __restrict__ Z) {
  int idx = blockIdx.x * 256 + threadIdx.x;
  if (idx >= BB * MM * DD) return;
  int b = idx / (MM * DD);
  int r = idx % (MM * DD);
  float s = 0.f;
  #pragma unroll
  for (int k = 0; k < SKC; k++) s += partial[(size_t)(b * SKC + k) * MM * DD + r];
  Z[idx] = s;
}

// ---------------- LN (rows of 128) ----------------
__global__ void k_ln1(const float* __restrict__ Z, const float* __restrict__ wgt,
                      const float* __restrict__ bias, float* __restrict__ Zin) {
  int row = blockIdx.x;
  int tid = threadIdx.x;
  float v = Z[(size_t)row * DD + tid];
  float s = v, q = v * v;
  for (int off = 32; off; off >>= 1) { s += __shfl_xor(s, off); q += __shfl_xor(q, off); }
  __shared__ float sh[4];
  int wv = tid >> 6;
  if ((tid & 63) == 0) { sh[wv] = s; sh[2 + wv] = q; }
  __syncthreads();
  s = sh[0] + sh[1]; q = sh[2] + sh[3];
  float mean = s / 128.f;
  float var = q / 128.f - mean * mean;
  float inv = rsqrtf(var + 1e-5f);
  Zin[(size_t)row * DD + tid] = (v - mean) * inv * wgt[tid] + bias[tid];
}

// ---------------- qkv projection ----------------
__global__ void k_qkv(const float* __restrict__ Zin, const float* __restrict__ W,
                      const float* __restrict__ bias, float* __restrict__ q,
                      float* __restrict__ k, float* __restrict__ v) {
  int row = blockIdx.x;            // b*M + t
  int b = row / MM, t = row % MM;
  int j = threadIdx.x;             // 0..383
  __shared__ float zr[128];
  if (j < 128) zr[j] = Zin[(size_t)row * DD + j];
  __syncthreads();
  float acc = bias[j];
  for (int i = 0; i < 128; i++) acc += zr[i] * W[(size_t)i * 384 + j];
  int which = j >> 7;
  int jj = j & 127;
  int hh = jj >> 4, dh = jj & 15;
  float* dst = (which == 0) ? q : (which == 1) ? k : v;
  dst[((size_t)(b * HHD + hh) * MM + t) * DHH + dh] = acc;
}

// ---------------- attention (per b,h; online softmax) ----------------
__global__ void k_att(const float* __restrict__ q, const float* __restrict__ k,
                      const float* __restrict__ v, float* __restrict__ obuf) {
  int bh = blockIdx.x; int b = bh / HHD, hh = bh % HHD;
  __shared__ float ks[MM * DHH];
  __shared__ float vs[MM * DHH];
  const float* kp = k + (size_t)bh * MM * DHH;
  const float* vp = v + (size_t)bh * MM * DHH;
  for (int i = threadIdx.x; i < MM * DHH; i += 256) { ks[i] = kp[i]; vs[i] = vp[i]; }
  __syncthreads();
  const float scale = 0.25f;
  for (int r = threadIdx.x; r < MM; r += 256) {
    float qr[16];
    const float* qp = q + ((size_t)bh * MM + r) * DHH;
    #pragma unroll
    for (int j = 0; j < 16; j++) qr[j] = qp[j];
    float m = -1e30f, s = 0.f, o[16];
    #pragma unroll
    for (int j = 0; j < 16; j++) o[j] = 0.f;
    for (int t = 0; t < MM; t++) {
      float sc = 0.f;
      #pragma unroll
      for (int j = 0; j < 16; j++) sc += qr[j] * ks[t * 16 + j];
      sc *= scale;
      float mn = fmaxf(m, sc);
      float corr = __expf(m - mn);
      float e = __expf(sc - mn);
      s = s * corr + e;
      #pragma unroll
      for (int j = 0; j < 16; j++) o[j] = o[j] * corr + e * vs[t * 16 + j];
      m = mn;
    }
    float invs = 1.f / s;
    float* op = obuf + ((size_t)(b * MM + r)) * DD + hh * DHH;
    #pragma unroll
    for (int j = 0; j < 16; j++) op[j] = o[j] * invs;
  }
}

// ---------------- attention out proj, accumulate into Z ----------------
__global__ void k_ao(const float* __restrict__ obuf, const float* __restrict__ W,
                     const float* __restrict__ bias, float* __restrict__ Z) {
  int row = blockIdx.x; int d = threadIdx.x;
  __shared__ float orow[128];
  orow[d] = obuf[(size_t)row * DD + d];
  __syncthreads();
  float acc = bias[d];
  for (int i = 0; i < 128; i++) acc += orow[i] * W[(size_t)i * DD + d];
  Z[(size_t)row * DD + d] += acc;
}

// ---------------- deslice: h += bases @ Z ----------------
__global__ void k_deslice(const float* __restrict__ bases, const float* __restrict__ Z,
                          float* __restrict__ h) {
  int xt = blockIdx.x, b = blockIdx.y;
  int x0 = xt * 64;
  __shared__ float Zs[32][128];
  __shared__ float bs[64][32];
  int tid = threadIdx.x;
  int d = tid & 127, g = tid >> 7;
  float acc[32];
  #pragma unroll
  for (int i = 0; i < 32; i++) acc[i] = 0.f;
  for (int t0 = 0; t0 < MM; t0 += 32) {
    int nt = MM - t0; if (nt > 32) nt = 32;
    for (int kk = tid; kk < 32 * 128; kk += 256) {
      int tl = kk >> 7, dd = kk & 127;
      Zs[tl][dd] = (tl < nt) ? Z[((size_t)b * MM + t0 + tl) * DD + dd] : 0.f;
    }
    const float* bp = bases + ((size_t)b * NN + x0) * MM + t0;
    for (int kk = tid; kk < 64 * 32; kk += 256) {
      int xl = kk >> 5, tl = kk & 31;
      bs[xl][tl] = (tl < nt) ? bp[(size_t)xl * MM + tl] : 0.f;
    }
    __syncthreads();
    for (int tl = 0; tl < 32; tl++) {
      float zv = Zs[tl][d];
      #pragma unroll
      for (int i = 0; i < 32; i++) acc[i] += zv * bs[g * 32 + i][tl];
    }
    __syncthreads();
  }
  float* hp = h + ((size_t)b * NN + x0 + g * 32) * DD + d;
  #pragma unroll
  for (int i = 0; i < 32; i++) hp[(size_t)i * DD] += acc[i];
}

// ---------------- FFN part A: mid = gelu(LN2(h) @ f1 + b1), mid in bf16 ----------------
__global__ void k_ffnA(const float* __restrict__ h, const float* __restrict__ W1,
                       const float* __restrict__ b1, const float* __restrict__ lw,
                       const float* __restrict__ lb, __hip_bfloat16* __restrict__ mid) {
  int ct = blockIdx.x, rt = blockIdx.y;
  int r0 = rt * 64, c0 = ct * 64;
  __shared__ float hs[64][132];     // padded: rows differ by 4 banks
  __shared__ float wsld[128][64];
  __shared__ float mrow[64], irow[64];
  int tid = threadIdx.x;
  const float* hp = h + (size_t)r0 * DD;
  for (int kk = tid; kk < 64 * 128; kk += 256) hs[kk >> 7][kk & 127] = hp[kk];
  for (int kk = tid; kk < 128 * 64; kk += 256) { int i = kk >> 6, c = kk & 63; wsld[i][c] = W1[(size_t)i * DFFN + c0 + c]; }
  __syncthreads();
  {
    int r = tid >> 2, qq = tid & 3;
    float s = 0.f, q2 = 0.f;
    for (int dd = qq * 32; dd < qq * 32 + 32; dd++) { float x = hs[r][dd]; s += x; q2 += x * x; }
    s += __shfl_xor(s, 1); q2 += __shfl_xor(q2, 1);
    s += __shfl_xor(s, 2); q2 += __shfl_xor(q2, 2);
    if (qq == 0) {
      float mean = s / 128.f;
      float var = q2 / 128.f - mean * mean;
      mrow[r] = mean; irow[r] = rsqrtf(var + 1e-5f);
    }
  }
  __syncthreads();
  for (int kk = tid; kk < 64 * 128; kk += 256) {
    int r = kk >> 7, dd = kk & 127;
    hs[r][dd] = (hs[r][dd] - mrow[r]) * irow[r] * lw[dd] + lb[dd];
  }
  __syncthreads();
  int tx = tid & 15, ty = tid >> 4;
  float acc[4][4];
  #pragma unroll
  for (int a = 0; a < 4; a++)
    #pragma unroll
    for (int c = 0; c < 4; c++) acc[a][c] = 0.f;
  for (int i = 0; i < 128; i++) {
    float4 wv = *(const float4*)&wsld[i][tx * 4];
    #pragma unroll
    for (int a = 0; a < 4; a++) {
      float av = hs[ty * 4 + a][i];
      acc[a][0] += av * wv.x; acc[a][1] += av * wv.y;
      acc[a][2] += av * wv.z; acc[a][3] += av * wv.w;
    }
  }
  #pragma unroll
  for (int a = 0; a < 4; a++) {
    int row = r0 + ty * 4 + a;
    #pragma unroll
    for (int c = 0; c < 4; c++) {
      int col = c0 + tx * 4 + c;
      float x = acc[a][c] + b1[col];
      float gl = 0.5f * x * (1.f + erff(x * 0.70710678118654752f));
      mid[(size_t)row * DFFN + col] = __float2bfloat16(gl);
    }
  }
}

// ---------------- FFN part B: h += mid @ f2 + b2 ----------------
__global__ void k_ffnB(const __hip_bfloat16* __restrict__ mid, const float* __restrict__ W2,
                       const float* __restrict__ b2, float* __restrict__ h) {
  int rt = blockIdx.x; int r0 = rt * 64;
  __shared__ float ms[64][64];
  __shared__ float fs[64][128];
  int tid = threadIdx.x;
  int tx = tid & 31, ty = tid >> 5;
  float acc[8][4];
  #pragma unroll
  for (int r = 0; r < 8; r++)
    #pragma unroll
    for (int c = 0; c < 4; c++) acc[r][c] = 0.f;
  for (int k0 = 0; k0 < DFFN; k0 += 64) {
    for (int kk = tid; kk < 64 * 64; kk += 256) {
      int r = kk >> 6, c = kk & 63;
      ms[r][c] = __bfloat162float(mid[(size_t)(r0 + r) * DFFN + k0 + c]);
    }
    for (int kk = tid; kk < 64 * 128; kk += 256) {
      int k = kk >> 7, c = kk & 127;
      fs[k][c] = W2[(size_t)(k0 + k) * DD + c];
    }
    __syncthreads();
    for (int k = 0; k < 64; k++) {
      float4 wv = *(const float4*)&fs[k][tx * 4];
      #pragma unroll
      for (int r = 0; r < 8; r++) {
        float a = ms[ty * 8 + r][k];
        acc[r][0] += a * wv.x; acc[r][1] += a * wv.y;
        acc[r][2] += a * wv.z; acc[r][3] += a * wv.w;
      }
    }
    __syncthreads();
  }
  #pragma unroll
  for (int r = 0; r < 8; r++) {
    int row = r0 + ty * 8 + r;
    float* hp = h + (size_t)row * DD + tx * 4;
    #pragma unroll
    for (int c = 0; c < 4; c++) hp[c] += acc[r][c] + b2[tx * 4 + c];
  }
}

// ---------------- final LN + out proj (f32 out) ----------------
__global__ void k_out(const float* __restrict__ h, const float* __restrict__ lw,
                      const float* __restrict__ lb, const float* __restrict__ ow,
                      const float* __restrict__ ob, float* __restrict__ out) {
  int row = blockIdx.x; int tid = threadIdx.x;
  float v = h[(size_t)row * DD + tid];
  float s = v, q = v * v;
  for (int off = 32; off; off >>= 1) { s += __shfl_xor(s, off); q += __shfl_xor(q, off); }
  __shared__ float sh[4];
  __shared__ float sp[4];
  int wv = tid >> 6;
  if ((tid & 63) == 0) { sh[wv] = s; sh[2 + wv] = q; }
  __syncthreads();
  s = sh[0] + sh[1]; q = sh[2] + sh[3];
  float mean = s / 128.f, var = q / 128.f - mean * mean;
  float inv = rsqrtf(var + 1e-5f);
  float ln = (v - mean) * inv * lw[tid] + lb[tid];
  float p0 = ln * ow[tid * 2 + 0], p1 = ln * ow[tid * 2 + 1];
  for (int off = 32; off; off >>= 1) { p0 += __shfl_xor(p0, off); p1 += __shfl_xor(p1, off); }
  if ((tid & 63) == 0) { sp[wv] = p0; sp[2 + wv] = p1; }
  __syncthreads();
  if (tid == 0) out[(size_t)row * 2 + 0] = sp[0] + sp[1] + ob[0];
  if (tid == 1) out[(size_t)row * 2 + 1] = sp[2] + sp[3] + ob[1];
}

extern "C" void kernel_launch(void* const* d_in, const int* in_sizes, int n_in,
                              void* d_out, int out_size, void* d_ws, size_t ws_size,
                              hipStream_t stream) {
  const float* u      = (const float*)d_in[0];
  const float* nodes  = (const float*)d_in[1];
  const float* nw     = (const float*)d_in[2];
  const float* modes  = (const float*)d_in[3];
  const float* coordB = (const float*)d_in[4];
  const float* cp_w   = (const float*)d_in[5];
  const float* cp_b   = (const float*)d_in[6];
  const float* in_w   = (const float*)d_in[7];
  const float* in_b   = (const float*)d_in[8];
  const float* ln1_w  = (const float*)d_in[9];
  const float* ln1_b  = (const float*)d_in[10];
  const float* qkv_w  = (const float*)d_in[11];
  const float* qkv_b  = (const float*)d_in[12];
  const float* ao_w   = (const float*)d_in[13];
  const float* ao_b   = (const float*)d_in[14];
  const float* f1_w   = (const float*)d_in[15];
  const float* f1_b   = (const float*)d_in[16];
  const float* f2_w   = (const float*)d_in[17];
  const float* f2_b   = (const float*)d_in[18];
  const float* ln2_w  = (const float*)d_in[19];
  const float* ln2_b  = (const float*)d_in[20];
  const float* lnf_w  = (const float*)d_in[21];
  const float* lnf_b  = (const float*)d_in[22];
  const float* out_w  = (const float*)d_in[23];
  const float* out_b  = (const float*)d_in[24];

  char* ws = (char*)d_ws;
  size_t off = 0;
  float* bases = (float*)(ws + off); off += (size_t)BB * NN * MM * 4;        // 67.37 MB
  float* h     = (float*)(ws + off); off += (size_t)BB * NN * DD * 4;        // 33.55 MB
  __hip_bfloat16* mid = (__hip_bfloat16*)(ws + off); off += (size_t)BB * NN * DFFN * 2; // 67.11 MB
  float* part  = (float*)(ws + off); off += (size_t)BB * SKC * MM * DD * 4;  // 33.69 MB
  float* Z     = (float*)(ws + off); off += (size_t)BB * MM * DD * 4;
  float* Zin   = (float*)(ws + off); off += (size_t)BB * MM * DD * 4;
  float* qb    = (float*)(ws + off); off += (size_t)BB * MM * DD * 4;
  float* kb    = (float*)(ws + off); off += (size_t)BB * MM * DD * 4;
  float* vb    = (float*)(ws + off); off += (size_t)BB * MM * DD * 4;
  float* ob2   = (float*)(ws + off); off += (size_t)BB * MM * DD * 4;

  k_embed<<<BB * NN, 128, 0, stream>>>(u, nodes, modes, coordB, cp_w, cp_b, in_w, in_b, bases, h);
  for (int l = 0; l < LL; l++) {
    k_slice<<<dim3(SKC, 9, BB), 256, 0, stream>>>(bases, h, nw, part);
    k_reduce<<<(BB * MM * DD + 255) / 256, 256, 0, stream>>>(part, Z);
    k_ln1<<<BB * MM, 128, 0, stream>>>(Z, ln1_w + l * DD, ln1_b + l * DD, Zin);
    k_qkv<<<BB * MM, 384, 0, stream>>>(Zin, qkv_w + (size_t)l * DD * 3 * DD, qkv_b + l * 3 * DD, qb, kb, vb);
    k_att<<<BB * HHD, 256, 0, stream>>>(qb, kb, vb, ob2);
    k_ao<<<BB * MM, 128, 0, stream>>>(ob2, ao_w + (size_t)l * DD * DD, ao_b + l * DD, Z);
    k_deslice<<<dim3(NN / 64, BB), 256, 0, stream>>>(bases, Z, h);
    k_ffnA<<<dim3(DFFN / 64, BB * NN / 64), 256, 0, stream>>>(h, f1_w + (size_t)l * DD * DFFN, f1_b + l * DFFN,
                                                              ln2_w + l * DD, ln2_b + l * DD, mid);
    k_ffnB<<<BB * NN / 64, 256, 0, stream>>>(mid, f2_w + (size_t)l * DFFN * DD, f2_b + l * DD, h);
  }
  k_out<<<BB * NN, 128, 0, stream>>>(h, lnf_w, lnf_b, out_w, out_b, (float*)d_out);
}

// Round 6
// 3603.465 us; speedup vs baseline: 1.4236x; 1.4236x over previous
//
#include <hip/hip_runtime.h>
#include <hip/hip_bf16.h>
#include <math.h>

#define BB 4
#define NN 16384
#define KM 128
#define DD 128
#define HHD 8
#define LL 6
#define DFFN 512
#define NFF 16
#define DCC 64
#define MM 257
#define DHH 16
#define SKC 16      // split-K chunks for slice
#define TPAD 320    // t-dim padded

typedef __hip_bfloat16 bf16;
using bf16x8 = __attribute__((ext_vector_type(8))) short;
using f32x4  = __attribute__((ext_vector_type(4))) float;

__device__ __forceinline__ void split2(float v, bf16& hi, bf16& lo) {
  hi = __float2bfloat16(v);
  lo = __float2bfloat16(v - __bfloat162float(hi));
}
__device__ __forceinline__ short b2s(bf16 x) {
  union { bf16 b; short s; } u; u.b = x; return u.s;
}

// ---------------- prep: bf16 hi/lo transposed FFN weights ----------------
__global__ void k_prepW(const float* __restrict__ f1_w, const float* __restrict__ f2_w,
                        bf16* __restrict__ f1T_hi, bf16* __restrict__ f1T_lo,
                        bf16* __restrict__ f2T_hi, bf16* __restrict__ f2T_lo) {
  size_t i = (size_t)blockIdx.x * 256 + threadIdx.x;
  size_t n = (size_t)LL * DFFN * DD;
  if (i < n) {
    int l = i / (DFFN * DD); int rem = i % (DFFN * DD); int f = rem / DD; int d = rem % DD;
    bf16 hi, lo; split2(f1_w[(size_t)l * DD * DFFN + (size_t)d * DFFN + f], hi, lo);
    f1T_hi[i] = hi; f1T_lo[i] = lo;
  } else if (i < 2 * n) {
    size_t j = i - n;
    int l = j / (DD * DFFN); int rem = j % (DD * DFFN); int d = rem / DFFN; int f = rem % DFFN;
    bf16 hi, lo; split2(f2_w[(size_t)l * DFFN * DD + (size_t)f * DD + d], hi, lo);
    f2T_hi[j] = hi; f2T_lo[j] = lo;
  }
}

// ---------------- embed: h0 ----------------
__global__ void k_embed(const float* __restrict__ u, const float* __restrict__ nodes,
                        const float* __restrict__ coordB,
                        const float* __restrict__ cp_w, const float* __restrict__ cp_b,
                        const float* __restrict__ in_w, const float* __restrict__ in_b,
                        float* __restrict__ h) {
  int p = blockIdx.x;
  int tid = threadIdx.x;       // 128
  float n0 = nodes[(size_t)p * 2 + 0], n1 = nodes[(size_t)p * 2 + 1];
  __shared__ float feats[34];
  __shared__ float hin[66];
  if (tid < NFF) {
    float xb = n0 * coordB[tid] + n1 * coordB[NFF + tid];
    feats[2 + tid] = sinf(xb);
    feats[2 + NFF + tid] = cosf(xb);
  }
  if (tid == 0) { feats[0] = n0; feats[1] = n1; hin[0] = u[(size_t)p * 2]; hin[1] = u[(size_t)p * 2 + 1]; }
  __syncthreads();
  if (tid < DCC) {
    float acc = cp_b[tid];
    #pragma unroll
    for (int i = 0; i < 34; i++) acc += feats[i] * cp_w[i * DCC + tid];
    hin[2 + tid] = acc;
  }
  __syncthreads();
  float acc = in_b[tid];
  #pragma unroll
  for (int i = 0; i < 66; i++) acc += hin[i] * in_w[i * DD + tid];
  h[(size_t)p * DD + tid] = acc;
}

__device__ __forceinline__ float basis_val(int t, float n0, float n1, const float* modes) {
  if (t >= 2 * KM) return (t == 2 * KM) ? 1.0f : 0.0f;
  int mi = t & (KM - 1);
  float th = n0 * modes[mi * 2 + 0] + n1 * modes[mi * 2 + 1];
  float s, c; __sincosf(th, &s, &c);
  return (t < KM) ? c : s;
}

// ---------------- basesT [b][t][x] hi/lo (slice B operand) ----------------
__global__ void k_basesT(const float* __restrict__ nodes, const float* __restrict__ modes,
                         bf16* __restrict__ bT_hi, bf16* __restrict__ bT_lo) {
  int t = blockIdx.y, b = blockIdx.z;
  int x = blockIdx.x * 256 + threadIdx.x;
  float2 nd = *(const float2*)(nodes + ((size_t)b * NN + x) * 2);
  float v = basis_val(t, nd.x, nd.y, modes);
  bf16 hi, lo; split2(v, hi, lo);
  size_t idx = ((size_t)b * TPAD + t) * NN + x;
  bT_hi[idx] = hi; bT_lo[idx] = lo;
}

// ---------------- hTw init: [d][x] = h*w, hi/lo ----------------
__global__ void k_hTw(const float* __restrict__ h, const float* __restrict__ nw,
                      bf16* __restrict__ hw_hi, bf16* __restrict__ hw_lo) {
  int xt = blockIdx.x, b = blockIdx.y; int x0 = xt * 64;
  __shared__ float T[128][67];
  __shared__ float wls[64];
  int tid = threadIdx.x;
  if (tid < 64) wls[tid] = nw[(size_t)b * NN + x0 + tid];
  for (int it = 0; it < 32; ++it) {
    int eid = it * 256 + tid; int x = eid >> 7, d = eid & 127;
    T[d][x] = h[((size_t)b * NN + x0 + x) * DD + d];
  }
  __syncthreads();
  for (int it = 0; it < 32; ++it) {
    int eid = it * 256 + tid; int d = eid >> 6, xl = eid & 63;
    float v = T[d][xl] * wls[xl];
    bf16 hi, lo; split2(v, hi, lo);
    size_t idx = ((size_t)b * DD + d) * NN + x0 + xl;
    hw_hi[idx] = hi; hw_lo[idx] = lo;
  }
}

// ---------------- slice (MFMA, no LDS): partialT[b][ck][d][t] ----------------
__global__ void k_slice(const bf16* __restrict__ bT_hi, const bf16* __restrict__ bT_lo,
                        const bf16* __restrict__ hw_hi, const bf16* __restrict__ hw_lo,
                        float* __restrict__ partialT) {
  int ck = blockIdx.x, tg = blockIdx.y, b = blockIdx.z;
  int kbase = ck * (NN / SKC);   // 1024-chunk of x
  int tid = threadIdx.x, w = tid >> 6, lane = tid & 63, lr = lane & 15, lg = lane >> 4;
  const bf16* pAh = hw_hi + ((size_t)b * DD + w * 32 + lr) * NN + kbase + lg * 8;
  const bf16* pAl = hw_lo + ((size_t)b * DD + w * 32 + lr) * NN + kbase + lg * 8;
  const bf16* pBh = bT_hi + ((size_t)b * TPAD + tg * 64 + lr) * NN + kbase + lg * 8;
  const bf16* pBl = bT_lo + ((size_t)b * TPAD + tg * 64 + lr) * NN + kbase + lg * 8;
  f32x4 acc[8];
  #pragma unroll
  for (int i = 0; i < 8; i++) acc[i] = (f32x4){0.f, 0.f, 0.f, 0.f};
  for (int kc = 0; kc < NN / SKC; kc += 64) {
    #pragma unroll
    for (int ks2 = 0; ks2 < 2; ++ks2) {
      int ko = kc + ks2 * 32;
      bf16x8 ah[2], al[2], bh[4], bl[4];
      #pragma unroll
      for (int fi = 0; fi < 2; ++fi) {
        ah[fi] = *(const bf16x8*)(pAh + (size_t)fi * 16 * NN + ko);
        al[fi] = *(const bf16x8*)(pAl + (size_t)fi * 16 * NN + ko);
      }
      #pragma unroll
      for (int tc = 0; tc < 4; ++tc) {
        bh[tc] = *(const bf16x8*)(pBh + (size_t)tc * 16 * NN + ko);
        bl[tc] = *(const bf16x8*)(pBl + (size_t)tc * 16 * NN + ko);
      }
      #pragma unroll
      for (int fi = 0; fi < 2; ++fi)
        #pragma unroll
        for (int tc = 0; tc < 4; ++tc) {
          int ai = fi * 4 + tc;
          acc[ai] = __builtin_amdgcn_mfma_f32_16x16x32_bf16(ah[fi], bh[tc], acc[ai], 0, 0, 0);
          acc[ai] = __builtin_amdgcn_mfma_f32_16x16x32_bf16(ah[fi], bl[tc], acc[ai], 0, 0, 0);
          acc[ai] = __builtin_amdgcn_mfma_f32_16x16x32_bf16(al[fi], bh[tc], acc[ai], 0, 0, 0);
        }
    }
  }
  float* pp = partialT + ((size_t)(b * SKC + ck) * DD) * TPAD;
  #pragma unroll
  for (int fi = 0; fi < 2; ++fi)
    #pragma unroll
    for (int tc = 0; tc < 4; ++tc)
      #pragma unroll
      for (int r = 0; r < 4; ++r) {
        int d = w * 32 + fi * 16 + lg * 4 + r;
        int t = tg * 64 + tc * 16 + lr;
        pp[(size_t)d * TPAD + t] = acc[fi * 4 + tc][r];
      }
}

// ---------------- reduce: Z[t][d] = sum_ck partialT[ck][d][t] ----------------
__global__ void k_reduce(const float* __restrict__ partialT, float* __restrict__ Z) {
  int idx = blockIdx.x * 256 + threadIdx.x;
  if (idx >= BB * DD * MM) return;
  int b = idx / (DD * MM); int rem = idx % (DD * MM); int d = rem / MM; int t = rem % MM;
  float s = 0.f;
  #pragma unroll
  for (int ck = 0; ck < SKC; ck++)
    s += partialT[((size_t)(b * SKC + ck) * DD + d) * TPAD + t];
  Z[((size_t)b * MM + t) * DD + d] = s;
}

// ---------------- LN1 ----------------
__global__ void k_ln1(const float* __restrict__ Z, const float* __restrict__ wgt,
                      const float* __restrict__ bias, float* __restrict__ Zin) {
  int row = blockIdx.x;
  int tid = threadIdx.x;
  float v = Z[(size_t)row * DD + tid];
  float s = v, q = v * v;
  for (int off = 32; off; off >>= 1) { s += __shfl_xor(s, off); q += __shfl_xor(q, off); }
  __shared__ float sh[4];
  int wv = tid >> 6;
  if ((tid & 63) == 0) { sh[wv] = s; sh[2 + wv] = q; }
  __syncthreads();
  s = sh[0] + sh[1]; q = sh[2] + sh[3];
  float mean = s / 128.f;
  float var = q / 128.f - mean * mean;
  float inv = rsqrtf(var + 1e-5f);
  Zin[(size_t)row * DD + tid] = (v - mean) * inv * wgt[tid] + bias[tid];
}

// ---------------- qkv ----------------
__global__ void k_qkv(const float* __restrict__ Zin, const float* __restrict__ W,
                      const float* __restrict__ bias, float* __restrict__ q,
                      float* __restrict__ k, float* __restrict__ v) {
  int row = blockIdx.x;            // b*M + t
  int b = row / MM, t = row % MM;
  int j = threadIdx.x;             // 0..383
  __shared__ float zr[128];
  if (j < 128) zr[j] = Zin[(size_t)row * DD + j];
  __syncthreads();
  float acc = bias[j];
  for (int i = 0; i < 128; i++) acc += zr[i] * W[(size_t)i * 384 + j];
  int which = j >> 7;
  int jj = j & 127;
  int hh = jj >> 4, dh = jj & 15;
  float* dst = (which == 0) ? q : (which == 1) ? k : v;
  dst[((size_t)(b * HHD + hh) * MM + t) * DHH + dh] = acc;
}

// ---------------- attention ----------------
__global__ void k_att(const float* __restrict__ q, const float* __restrict__ k,
                      const float* __restrict__ v, float* __restrict__ obuf) {
  int bh = blockIdx.x; int b = bh / HHD, hh = bh % HHD;
  __shared__ float ks[MM * DHH];
  __shared__ float vs[MM * DHH];
  const float* kp = k + (size_t)bh * MM * DHH;
  const float* vp = v + (size_t)bh * MM * DHH;
  for (int i = threadIdx.x; i < MM * DHH; i += 256) { ks[i] = kp[i]; vs[i] = vp[i]; }
  __syncthreads();
  const float scale = 0.25f;
  for (int r = threadIdx.x; r < MM; r += 256) {
    float qr[16];
    const float* qp = q + ((size_t)bh * MM + r) * DHH;
    #pragma unroll
    for (int j = 0; j < 16; j++) qr[j] = qp[j];
    float m = -1e30f, s = 0.f, o[16];
    #pragma unroll
    for (int j = 0; j < 16; j++) o[j] = 0.f;
    for (int t = 0; t < MM; t++) {
      float sc = 0.f;
      #pragma unroll
      for (int j = 0; j < 16; j++) sc += qr[j] * ks[t * 16 + j];
      sc *= scale;
      float mn = fmaxf(m, sc);
      float corr = __expf(m - mn);
      float e = __expf(sc - mn);
      s = s * corr + e;
      #pragma unroll
      for (int j = 0; j < 16; j++) o[j] = o[j] * corr + e * vs[t * 16 + j];
      m = mn;
    }
    float invs = 1.f / s;
    float* op = obuf + ((size_t)(b * MM + r)) * DD + hh * DHH;
    #pragma unroll
    for (int j = 0; j < 16; j++) op[j] = o[j] * invs;
  }
}

// ---------------- attn out proj -> Z ----------------
__global__ void k_ao(const float* __restrict__ obuf, const float* __restrict__ W,
                     const float* __restrict__ bias, float* __restrict__ Z) {
  int row = blockIdx.x; int d = threadIdx.x;
  __shared__ float orow[128];
  orow[d] = obuf[(size_t)row * DD + d];
  __syncthreads();
  float acc = bias[d];
  for (int i = 0; i < 128; i++) acc += orow[i] * W[(size_t)i * DD + d];
  Z[(size_t)row * DD + d] += acc;
}

// ---------------- Zt hi/lo [d][t-pad] ----------------
__global__ void k_zt(const float* __restrict__ Z, bf16* __restrict__ Zt_hi,
                     bf16* __restrict__ Zt_lo) {
  int dg = blockIdx.x; int b = blockIdx.y;
  int tid = threadIdx.x;
  for (int it = 0; it < 20; ++it) {
    int eid = it * 256 + tid;           // 16*320
    int d = dg * 16 + eid / TPAD; int t = eid % TPAD;
    float v = (t < MM) ? Z[((size_t)b * MM + t) * DD + d] : 0.f;
    bf16 hi, lo; split2(v, hi, lo);
    size_t idx = ((size_t)b * DD + d) * TPAD + t;
    Zt_hi[idx] = hi; Zt_lo[idx] = lo;
  }
}

// ------- deslice (MFMA, LDS-staged bases) + fused LN2 -> ln2h bf16 -------
__global__ void k_deslice(const float* __restrict__ nodes, const float* __restrict__ modes,
                          const bf16* __restrict__ Zt_hi, const bf16* __restrict__ Zt_lo,
                          const float* __restrict__ lw, const float* __restrict__ lb,
                          float* __restrict__ h, bf16* __restrict__ ln2h) {
  int xt = blockIdx.x, b = blockIdx.y;
  int x0 = xt * 64;
  int tid = threadIdx.x, w = tid >> 6, lane = tid & 63, lr = lane & 15, lg = lane >> 4;
  __shared__ float4 modes4[TPAD];   // (m0, m1, sel, mask)
  __shared__ float n0s[64], n1s[64];
  __shared__ short As_hi[64][72];   // row stride 144 B (16-mult)
  __shared__ short As_lo[64][72];
  for (int t = tid; t < TPAD; t += 256) {
    float m0 = 0.f, m1 = 0.f, sel = 0.f, mask = 0.f;
    if (t < 128)      { m0 = modes[2 * t];          m1 = modes[2 * t + 1];          mask = 1.f; }
    else if (t < 256) { m0 = modes[2 * (t - 128)];  m1 = modes[2 * (t - 128) + 1];  sel = 1.f; mask = 1.f; }
    else if (t == 256) { mask = 1.f; }              // constant-1 column
    modes4[t] = make_float4(m0, m1, sel, mask);
  }
  if (tid < 64) {
    n0s[tid] = nodes[((size_t)b * NN + x0 + tid) * 2 + 0];
    n1s[tid] = nodes[((size_t)b * NN + x0 + tid) * 2 + 1];
  }
  __syncthreads();
  const bf16* pBh = Zt_hi + ((size_t)b * DD + lr) * TPAD + lg * 8;
  const bf16* pBl = Zt_lo + ((size_t)b * DD + lr) * TPAD + lg * 8;
  f32x4 acc[8];
  #pragma unroll
  for (int i = 0; i < 8; i++) acc[i] = (f32x4){0.f, 0.f, 0.f, 0.f};
  for (int kc = 0; kc < TPAD; kc += 64) {
    __syncthreads();
    #pragma unroll
    for (int it = 0; it < 16; ++it) {
      int eid = it * 256 + tid;       // 4096 = 64 rows x 64 t
      int row = eid >> 6, tl = eid & 63;
      float4 md = modes4[kc + tl];
      float th = n0s[row] * md.x + n1s[row] * md.y;
      float s, c; __sincosf(th, &s, &c);
      float v = md.w * (c + md.z * (s - c));
      bf16 hi, lo; split2(v, hi, lo);
      As_hi[row][tl] = b2s(hi); As_lo[row][tl] = b2s(lo);
    }
    __syncthreads();
    #pragma unroll
    for (int ks2 = 0; ks2 < 2; ++ks2) {
      int ko = kc + ks2 * 32;
      bf16x8 ah = *(const bf16x8*)&As_hi[w * 16 + lr][ks2 * 32 + lg * 8];
      bf16x8 al = *(const bf16x8*)&As_lo[w * 16 + lr][ks2 * 32 + lg * 8];
      #pragma unroll
      for (int fi = 0; fi < 8; ++fi) {
        bf16x8 bh = *(const bf16x8*)(pBh + (size_t)fi * 16 * TPAD + ko);
        bf16x8 bl = *(const bf16x8*)(pBl + (size_t)fi * 16 * TPAD + ko);
        acc[fi] = __builtin_amdgcn_mfma_f32_16x16x32_bf16(ah, bh, acc[fi], 0, 0, 0);
        acc[fi] = __builtin_amdgcn_mfma_f32_16x16x32_bf16(ah, bl, acc[fi], 0, 0, 0);
        acc[fi] = __builtin_amdgcn_mfma_f32_16x16x32_bf16(al, bh, acc[fi], 0, 0, 0);
      }
    }
  }
  // epilogue: h += delta; LN2 per x-row; write h f32 + ln2h bf16
  float lwv[8], lbv[8];
  #pragma unroll
  for (int fi = 0; fi < 8; ++fi) { lwv[fi] = lw[fi * 16 + lr]; lbv[fi] = lb[fi * 16 + lr]; }
  float hv[8][4];
  float sm[4], sq[4];
  #pragma unroll
  for (int r = 0; r < 4; ++r) { sm[r] = 0.f; sq[r] = 0.f; }
  size_t rowbase = ((size_t)b * NN + x0 + w * 16 + lg * 4);
  #pragma unroll
  for (int fi = 0; fi < 8; ++fi)
    #pragma unroll
    for (int r = 0; r < 4; ++r) {
      float v = h[(rowbase + r) * DD + fi * 16 + lr] + acc[fi][r];
      hv[fi][r] = v; sm[r] += v; sq[r] += v * v;
    }
  #pragma unroll
  for (int r = 0; r < 4; ++r) {
    float s = sm[r], q = sq[r];
    s += __shfl_xor(s, 1); q += __shfl_xor(q, 1);
    s += __shfl_xor(s, 2); q += __shfl_xor(q, 2);
    s += __shfl_xor(s, 4); q += __shfl_xor(q, 4);
    s += __shfl_xor(s, 8); q += __shfl_xor(q, 8);
    float mean = s / 128.f;
    float var = q / 128.f - mean * mean;
    sm[r] = mean; sq[r] = rsqrtf(var + 1e-5f);
  }
  #pragma unroll
  for (int fi = 0; fi < 8; ++fi)
    #pragma unroll
    for (int r = 0; r < 4; ++r) {
      float v = hv[fi][r];
      h[(rowbase + r) * DD + fi * 16 + lr] = v;
      float ln = (v - sm[r]) * sq[r] * lwv[fi] + lbv[fi];
      ln2h[(rowbase + r) * DD + fi * 16 + lr] = __float2bfloat16(ln);
    }
}

// ---------------- ffnA (MFMA): mid = gelu(ln2h @ f1 + b1) bf16 ----------------
__global__ void k_ffnA(const bf16* __restrict__ ln2h, const bf16* __restrict__ f1T_hi,
                       const bf16* __restrict__ f1T_lo, const float* __restrict__ b1,
                       bf16* __restrict__ mid) {
  int x0 = blockIdx.x * 16;
  int tid = threadIdx.x, w = tid >> 6, lane = tid & 63, lr = lane & 15, lg = lane >> 4;
  int f0 = w * 128;
  const bf16* Arow = ln2h + ((size_t)x0 + lr) * DD;
  f32x4 acc[8];
  #pragma unroll
  for (int i = 0; i < 8; i++) acc[i] = (f32x4){0.f, 0.f, 0.f, 0.f};
  #pragma unroll
  for (int ks = 0; ks < 4; ++ks) {
    bf16x8 a = *(const bf16x8*)(Arow + ks * 32 + lg * 8);
    #pragma unroll
    for (int fi = 0; fi < 8; ++fi) {
      size_t widx = (size_t)(f0 + fi * 16 + lr) * DD + ks * 32 + lg * 8;
      bf16x8 bh = *(const bf16x8*)(f1T_hi + widx);
      bf16x8 bl = *(const bf16x8*)(f1T_lo + widx);
      acc[fi] = __builtin_amdgcn_mfma_f32_16x16x32_bf16(a, bh, acc[fi], 0, 0, 0);
      acc[fi] = __builtin_amdgcn_mfma_f32_16x16x32_bf16(a, bl, acc[fi], 0, 0, 0);
    }
  }
  #pragma unroll
  for (int fi = 0; fi < 8; ++fi) {
    int col = f0 + fi * 16 + lr;
    float bb = b1[col];
    #pragma unroll
    for (int r = 0; r < 4; ++r) {
      int x = x0 + lg * 4 + r;
      float xx = acc[fi][r] + bb;
      float gl = 0.5f * xx * (1.f + erff(xx * 0.70710678118654752f));
      mid[(size_t)x * DFFN + col] = __float2bfloat16(gl);
    }
  }
}

// ------- ffnB (MFMA): h += mid @ f2 + b2; write hw hi/lo -------
__global__ void k_ffnB(const bf16* __restrict__ mid, const bf16* __restrict__ f2T_hi,
                       const bf16* __restrict__ f2T_lo, const float* __restrict__ b2,
                       const float* __restrict__ nw, float* __restrict__ h,
                       bf16* __restrict__ hw_hi, bf16* __restrict__ hw_lo) {
  int x0 = blockIdx.x * 64;
  int b = x0 / NN; int xb = x0 % NN;
  int tid = threadIdx.x, w = tid >> 6, lane = tid & 63, lr = lane & 15, lg = lane >> 4;
  __shared__ float T[128][67];
  __shared__ float wls[64];
  if (tid < 64) wls[tid] = nw[(size_t)b * NN + xb + tid];
  const bf16* Arow = mid + ((size_t)x0 + w * 16 + lr) * DFFN;
  f32x4 acc[8];
  #pragma unroll
  for (int i = 0; i < 8; i++) acc[i] = (f32x4){0.f, 0.f, 0.f, 0.f};
  #pragma unroll
  for (int ks = 0; ks < 16; ++ks) {
    bf16x8 a = *(const bf16x8*)(Arow + ks * 32 + lg * 8);
    #pragma unroll
    for (int fi = 0; fi < 8; ++fi) {
      size_t widx = (size_t)(fi * 16 + lr) * DFFN + ks * 32 + lg * 8;
      bf16x8 bh = *(const bf16x8*)(f2T_hi + widx);
      bf16x8 bl = *(const bf16x8*)(f2T_lo + widx);
      acc[fi] = __builtin_amdgcn_mfma_f32_16x16x32_bf16(a, bh, acc[fi], 0, 0, 0);
      acc[fi] = __builtin_amdgcn_mfma_f32_16x16x32_bf16(a, bl, acc[fi], 0, 0, 0);
    }
  }
  size_t rowbase = (size_t)x0 + w * 16 + lg * 4;
  #pragma unroll
  for (int fi = 0; fi < 8; ++fi) {
    int d = fi * 16 + lr;
    float bb = b2[d];
    #pragma unroll
    for (int r = 0; r < 4; ++r) {
      float v = h[(rowbase + r) * DD + d] + acc[fi][r] + bb;
      h[(rowbase + r) * DD + d] = v;
      T[d][w * 16 + lg * 4 + r] = v;
    }
  }
  __syncthreads();
  for (int it = 0; it < 32; ++it) {
    int eid = it * 256 + tid; int d = eid >> 6, xl = eid & 63;
    float v = T[d][xl] * wls[xl];
    bf16 hi, lo; split2(v, hi, lo);
    size_t idx = ((size_t)b * DD + d) * NN + xb + xl;
    hw_hi[idx] = hi; hw_lo[idx] = lo;
  }
}

// ---------------- final LN + out proj (f32 out) ----------------
__global__ void k_out(const float* __restrict__ h, const float* __restrict__ lw,
                      const float* __restrict__ lb, const float* __restrict__ ow,
                      const float* __restrict__ ob, float* __restrict__ out) {
  int row = blockIdx.x; int tid = threadIdx.x;
  float v = h[(size_t)row * DD + tid];
  float s = v, q = v * v;
  for (int off = 32; off; off >>= 1) { s += __shfl_xor(s, off); q += __shfl_xor(q, off); }
  __shared__ float sh[4];
  __shared__ float sp[4];
  int wv = tid >> 6;
  if ((tid & 63) == 0) { sh[wv] = s; sh[2 + wv] = q; }
  __syncthreads();
  s = sh[0] + sh[1]; q = sh[2] + sh[3];
  float mean = s / 128.f, var = q / 128.f - mean * mean;
  float inv = rsqrtf(var + 1e-5f);
  float ln = (v - mean) * inv * lw[tid] + lb[tid];
  float p0 = ln * ow[tid * 2 + 0], p1 = ln * ow[tid * 2 + 1];
  for (int off = 32; off; off >>= 1) { p0 += __shfl_xor(p0, off); p1 += __shfl_xor(p1, off); }
  if ((tid & 63) == 0) { sp[wv] = p0; sp[2 + wv] = p1; }
  __syncthreads();
  if (tid == 0) out[(size_t)row * 2 + 0] = sp[0] + sp[1] + ob[0];
  if (tid == 1) out[(size_t)row * 2 + 1] = sp[2] + sp[3] + ob[1];
}

extern "C" void kernel_launch(void* const* d_in, const int* in_sizes, int n_in,
                              void* d_out, int out_size, void* d_ws, size_t ws_size,
                              hipStream_t stream) {
  const float* u      = (const float*)d_in[0];
  const float* nodes  = (const float*)d_in[1];
  const float* nw     = (const float*)d_in[2];
  const float* modes  = (const float*)d_in[3];
  const float* coordB = (const float*)d_in[4];
  const float* cp_w   = (const float*)d_in[5];
  const float* cp_b   = (const float*)d_in[6];
  const float* in_w   = (const float*)d_in[7];
  const float* in_b   = (const float*)d_in[8];
  const float* ln1_w  = (const float*)d_in[9];
  const float* ln1_b  = (const float*)d_in[10];
  const float* qkv_w  = (const float*)d_in[11];
  const float* qkv_b  = (const float*)d_in[12];
  const float* ao_w   = (const float*)d_in[13];
  const float* ao_b   = (const float*)d_in[14];
  const float* f1_w   = (const float*)d_in[15];
  const float* f1_b   = (const float*)d_in[16];
  const float* f2_w   = (const float*)d_in[17];
  const float* f2_b   = (const float*)d_in[18];
  const float* ln2_w  = (const float*)d_in[19];
  const float* ln2_b  = (const float*)d_in[20];
  const float* lnf_w  = (const float*)d_in[21];
  const float* lnf_b  = (const float*)d_in[22];
  const float* out_w  = (const float*)d_in[23];
  const float* out_b  = (const float*)d_in[24];

  char* ws = (char*)d_ws;
  size_t off = 0;
  bf16* bT_hi = (bf16*)(ws + off); off += (size_t)BB * TPAD * NN * 2;   // 41.9 MB
  bf16* bT_lo = (bf16*)(ws + off); off += (size_t)BB * TPAD * NN * 2;   // 41.9 MB
  float* h    = (float*)(ws + off); off += (size_t)BB * NN * DD * 4;    // 33.6 MB
  bf16* hw_hi = (bf16*)(ws + off); off += (size_t)BB * DD * NN * 2;     // 16.8 MB
  bf16* hw_lo = (bf16*)(ws + off); off += (size_t)BB * DD * NN * 2;     // 16.8 MB
  bf16* ln2h  = (bf16*)(ws + off); off += (size_t)BB * NN * DD * 2;     // 16.8 MB
  // regMid: partialT (33.6) | mid (67.1) | attention smalls @+40MB — disjoint lifetimes
  char* regMid = ws + off; off += (size_t)BB * NN * DFFN * 2;           // 67.1 MB
  float* partialT = (float*)regMid;                       // live: slice -> reduce
  bf16*  mid      = (bf16*)regMid;                        // live: ffnA -> ffnB
  float* Zin = (float*)(regMid + 40 * 1024 * 1024);       // live: ln1 -> qkv
  float* qb  = Zin + (size_t)BB * MM * DD;                // live: qkv -> att
  float* kb  = qb  + (size_t)BB * MM * DD;
  float* vb  = kb  + (size_t)BB * MM * DD;
  float* ob2 = vb  + (size_t)BB * MM * DD;                // live: att -> ao
  float* Z    = (float*)(ws + off); off += (size_t)BB * MM * DD * 4;
  bf16* Zt_hi = (bf16*)(ws + off); off += (size_t)BB * DD * TPAD * 2;
  bf16* Zt_lo = (bf16*)(ws + off); off += (size_t)BB * DD * TPAD * 2;
  bf16* f1T_hi = (bf16*)(ws + off); off += (size_t)LL * DFFN * DD * 2;
  bf16* f1T_lo = (bf16*)(ws + off); off += (size_t)LL * DFFN * DD * 2;
  bf16* f2T_hi = (bf16*)(ws + off); off += (size_t)LL * DD * DFFN * 2;
  bf16* f2T_lo = (bf16*)(ws + off); off += (size_t)LL * DD * DFFN * 2;
  // total ~239.2 MB (< 240.07 MB proven available in round 3)

  k_prepW<<<(2 * LL * DFFN * DD + 255) / 256, 256, 0, stream>>>(f1_w, f2_w, f1T_hi, f1T_lo, f2T_hi, f2T_lo);
  k_embed<<<BB * NN, 128, 0, stream>>>(u, nodes, coordB, cp_w, cp_b, in_w, in_b, h);
  k_basesT<<<dim3(NN / 256, TPAD, BB), 256, 0, stream>>>(nodes, modes, bT_hi, bT_lo);
  k_hTw<<<dim3(NN / 64, BB), 256, 0, stream>>>(h, nw, hw_hi, hw_lo);

  for (int l = 0; l < LL; l++) {
    k_slice<<<dim3(SKC, TPAD / 64, BB), 256, 0, stream>>>(bT_hi, bT_lo, hw_hi, hw_lo, partialT);
    k_reduce<<<(BB * DD * MM + 255) / 256, 256, 0, stream>>>(partialT, Z);
    k_ln1<<<BB * MM, 128, 0, stream>>>(Z, ln1_w + l * DD, ln1_b + l * DD, Zin);
    k_qkv<<<BB * MM, 384, 0, stream>>>(Zin, qkv_w + (size_t)l * DD * 3 * DD, qkv_b + l * 3 * DD, qb, kb, vb);
    k_att<<<BB * HHD, 256, 0, stream>>>(qb, kb, vb, ob2);
    k_ao<<<BB * MM, 128, 0, stream>>>(ob2, ao_w + (size_t)l * DD * DD, ao_b + l * DD, Z);
    k_zt<<<dim3(8, BB), 256, 0, stream>>>(Z, Zt_hi, Zt_lo);
    k_deslice<<<dim3(NN / 64, BB), 256, 0, stream>>>(nodes, modes, Zt_hi, Zt_lo,
                                                     ln2_w + l * DD, ln2_b + l * DD, h, ln2h);
    k_ffnA<<<BB * NN / 16, 256, 0, stream>>>(ln2h, f1T_hi + (size_t)l * DFFN * DD,
                                             f1T_lo + (size_t)l * DFFN * DD, f1_b + l * DFFN, mid);
    k_ffnB<<<BB * NN / 64, 256, 0, stream>>>(mid, f2T_hi + (size_t)l * DD * DFFN,
                                             f2T_lo + (size_t)l * DD * DFFN, f2_b + l * DD,
                                             nw, h, hw_hi, hw_lo);
  }
  k_out<<<BB * NN, 128, 0, stream>>>(h, lnf_w, lnf_b, out_w, out_b, (float*)d_out);
}

// Round 7
// 3596.693 us; speedup vs baseline: 1.4263x; 1.0019x over previous
//
#include <hip/hip_runtime.h>
#include <hip/hip_bf16.h>
#include <math.h>

#define BB 4
#define NN 16384
#define KM 128
#define DD 128
#define HHD 8
#define LL 6
#define DFFN 512
#define NFF 16
#define DCC 64
#define MM 257
#define DHH 16
#define SKC 16      // split-K chunks for slice
#define TPAD 320    // t-dim padded

typedef __hip_bfloat16 bf16;
using bf16x8 = __attribute__((ext_vector_type(8))) short;
using f32x4  = __attribute__((ext_vector_type(4))) float;

__device__ __forceinline__ void split2(float v, bf16& hi, bf16& lo) {
  hi = __float2bfloat16(v);
  lo = __float2bfloat16(v - __bfloat162float(hi));
}
__device__ __forceinline__ short b2s(bf16 x) {
  union { bf16 b; short s; } u; u.b = x; return u.s;
}

// ---------------- prep: bf16 hi/lo transposed FFN weights ----------------
__global__ void k_prepW(const float* __restrict__ f1_w, const float* __restrict__ f2_w,
                        bf16* __restrict__ f1T_hi, bf16* __restrict__ f1T_lo,
                        bf16* __restrict__ f2T_hi, bf16* __restrict__ f2T_lo) {
  size_t i = (size_t)blockIdx.x * 256 + threadIdx.x;
  size_t n = (size_t)LL * DFFN * DD;
  if (i < n) {
    int l = i / (DFFN * DD); int rem = i % (DFFN * DD); int f = rem / DD; int d = rem % DD;
    bf16 hi, lo; split2(f1_w[(size_t)l * DD * DFFN + (size_t)d * DFFN + f], hi, lo);
    f1T_hi[i] = hi; f1T_lo[i] = lo;
  } else if (i < 2 * n) {
    size_t j = i - n;
    int l = j / (DD * DFFN); int rem = j % (DD * DFFN); int d = rem / DFFN; int f = rem % DFFN;
    bf16 hi, lo; split2(f2_w[(size_t)l * DFFN * DD + (size_t)f * DD + d], hi, lo);
    f2T_hi[j] = hi; f2T_lo[j] = lo;
  }
}

// ---------------- embed: h0 ----------------
__global__ void k_embed(const float* __restrict__ u, const float* __restrict__ nodes,
                        const float* __restrict__ coordB,
                        const float* __restrict__ cp_w, const float* __restrict__ cp_b,
                        const float* __restrict__ in_w, const float* __restrict__ in_b,
                        float* __restrict__ h) {
  int p = blockIdx.x;
  int tid = threadIdx.x;       // 128
  float n0 = nodes[(size_t)p * 2 + 0], n1 = nodes[(size_t)p * 2 + 1];
  __shared__ float feats[34];
  __shared__ float hin[66];
  if (tid < NFF) {
    float xb = n0 * coordB[tid] + n1 * coordB[NFF + tid];
    feats[2 + tid] = sinf(xb);
    feats[2 + NFF + tid] = cosf(xb);
  }
  if (tid == 0) { feats[0] = n0; feats[1] = n1; hin[0] = u[(size_t)p * 2]; hin[1] = u[(size_t)p * 2 + 1]; }
  __syncthreads();
  if (tid < DCC) {
    float acc = cp_b[tid];
    #pragma unroll
    for (int i = 0; i < 34; i++) acc += feats[i] * cp_w[i * DCC + tid];
    hin[2 + tid] = acc;
  }
  __syncthreads();
  float acc = in_b[tid];
  #pragma unroll
  for (int i = 0; i < 66; i++) acc += hin[i] * in_w[i * DD + tid];
  h[(size_t)p * DD + tid] = acc;
}

__device__ __forceinline__ float basis_val(int t, float n0, float n1, const float* modes) {
  if (t >= 2 * KM) return (t == 2 * KM) ? 1.0f : 0.0f;
  int mi = t & (KM - 1);
  float th = n0 * modes[mi * 2 + 0] + n1 * modes[mi * 2 + 1];
  float s, c; __sincosf(th, &s, &c);
  return (t < KM) ? c : s;
}

// ---------------- basesT [b][t][x] hi/lo (slice B operand) ----------------
__global__ void k_basesT(const float* __restrict__ nodes, const float* __restrict__ modes,
                         bf16* __restrict__ bT_hi, bf16* __restrict__ bT_lo) {
  int t = blockIdx.y, b = blockIdx.z;
  int x = blockIdx.x * 256 + threadIdx.x;
  float2 nd = *(const float2*)(nodes + ((size_t)b * NN + x) * 2);
  float v = basis_val(t, nd.x, nd.y, modes);
  bf16 hi, lo; split2(v, hi, lo);
  size_t idx = ((size_t)b * TPAD + t) * NN + x;
  bT_hi[idx] = hi; bT_lo[idx] = lo;
}

// ---------------- hTw init: [d][x] = h*w, hi/lo ----------------
__global__ void k_hTw(const float* __restrict__ h, const float* __restrict__ nw,
                      bf16* __restrict__ hw_hi, bf16* __restrict__ hw_lo) {
  int xt = blockIdx.x, b = blockIdx.y; int x0 = xt * 64;
  __shared__ float T[128][67];
  __shared__ float wls[64];
  int tid = threadIdx.x;
  if (tid < 64) wls[tid] = nw[(size_t)b * NN + x0 + tid];
  for (int it = 0; it < 32; ++it) {
    int eid = it * 256 + tid; int x = eid >> 7, d = eid & 127;
    T[d][x] = h[((size_t)b * NN + x0 + x) * DD + d];
  }
  __syncthreads();
  for (int it = 0; it < 32; ++it) {
    int eid = it * 256 + tid; int d = eid >> 6, xl = eid & 63;
    float v = T[d][xl] * wls[xl];
    bf16 hi, lo; split2(v, hi, lo);
    size_t idx = ((size_t)b * DD + d) * NN + x0 + xl;
    hw_hi[idx] = hi; hw_lo[idx] = lo;
  }
}

// ---------------- slice (MFMA, no LDS): partialT[b][ck][d][t] ----------------
__global__ void __launch_bounds__(256, 4)
k_slice(const bf16* __restrict__ bT_hi, const bf16* __restrict__ bT_lo,
        const bf16* __restrict__ hw_hi, const bf16* __restrict__ hw_lo,
        float* __restrict__ partialT) {
  int ck = blockIdx.x, tg = blockIdx.y, b = blockIdx.z;
  int kbase = ck * (NN / SKC);   // 1024-chunk of x
  int tid = threadIdx.x, w = tid >> 6, lane = tid & 63, lr = lane & 15, lg = lane >> 4;
  const bf16* pAh = hw_hi + ((size_t)b * DD + w * 32 + lr) * NN + kbase + lg * 8;
  const bf16* pAl = hw_lo + ((size_t)b * DD + w * 32 + lr) * NN + kbase + lg * 8;
  const bf16* pBh = bT_hi + ((size_t)b * TPAD + tg * 64 + lr) * NN + kbase + lg * 8;
  const bf16* pBl = bT_lo + ((size_t)b * TPAD + tg * 64 + lr) * NN + kbase + lg * 8;
  f32x4 acc[8];
  #pragma unroll
  for (int i = 0; i < 8; i++) acc[i] = (f32x4){0.f, 0.f, 0.f, 0.f};
  for (int kc = 0; kc < NN / SKC; kc += 64) {
    #pragma unroll
    for (int ks2 = 0; ks2 < 2; ++ks2) {
      int ko = kc + ks2 * 32;
      bf16x8 ah[2], al[2], bh[4], bl[4];
      #pragma unroll
      for (int fi = 0; fi < 2; ++fi) {
        ah[fi] = *(const bf16x8*)(pAh + (size_t)fi * 16 * NN + ko);
        al[fi] = *(const bf16x8*)(pAl + (size_t)fi * 16 * NN + ko);
      }
      #pragma unroll
      for (int tc = 0; tc < 4; ++tc) {
        bh[tc] = *(const bf16x8*)(pBh + (size_t)tc * 16 * NN + ko);
        bl[tc] = *(const bf16x8*)(pBl + (size_t)tc * 16 * NN + ko);
      }
      #pragma unroll
      for (int fi = 0; fi < 2; ++fi)
        #pragma unroll
        for (int tc = 0; tc < 4; ++tc) {
          int ai = fi * 4 + tc;
          acc[ai] = __builtin_amdgcn_mfma_f32_16x16x32_bf16(ah[fi], bh[tc], acc[ai], 0, 0, 0);
          acc[ai] = __builtin_amdgcn_mfma_f32_16x16x32_bf16(ah[fi], bl[tc], acc[ai], 0, 0, 0);
          acc[ai] = __builtin_amdgcn_mfma_f32_16x16x32_bf16(al[fi], bh[tc], acc[ai], 0, 0, 0);
        }
    }
  }
  float* pp = partialT + ((size_t)(b * SKC + ck) * DD) * TPAD;
  #pragma unroll
  for (int fi = 0; fi < 2; ++fi)
    #pragma unroll
    for (int tc = 0; tc < 4; ++tc)
      #pragma unroll
      for (int r = 0; r < 4; ++r) {
        int d = w * 32 + fi * 16 + lg * 4 + r;
        int t = tg * 64 + tc * 16 + lr;
        pp[(size_t)d * TPAD + t] = acc[fi * 4 + tc][r];
      }
}

// ---------------- reduce: Z[t][d] = sum_ck partialT[ck][d][t] ----------------
__global__ void k_reduce(const float* __restrict__ partialT, float* __restrict__ Z) {
  int idx = blockIdx.x * 256 + threadIdx.x;
  if (idx >= BB * DD * MM) return;
  int b = idx / (DD * MM); int rem = idx % (DD * MM); int d = rem / MM; int t = rem % MM;
  float s = 0.f;
  #pragma unroll
  for (int ck = 0; ck < SKC; ck++)
    s += partialT[((size_t)(b * SKC + ck) * DD + d) * TPAD + t];
  Z[((size_t)b * MM + t) * DD + d] = s;
}

// ---------------- LN1 ----------------
__global__ void k_ln1(const float* __restrict__ Z, const float* __restrict__ wgt,
                      const float* __restrict__ bias, float* __restrict__ Zin) {
  int row = blockIdx.x;
  int tid = threadIdx.x;
  float v = Z[(size_t)row * DD + tid];
  float s = v, q = v * v;
  for (int off = 32; off; off >>= 1) { s += __shfl_xor(s, off); q += __shfl_xor(q, off); }
  __shared__ float sh[4];
  int wv = tid >> 6;
  if ((tid & 63) == 0) { sh[wv] = s; sh[2 + wv] = q; }
  __syncthreads();
  s = sh[0] + sh[1]; q = sh[2] + sh[3];
  float mean = s / 128.f;
  float var = q / 128.f - mean * mean;
  float inv = rsqrtf(var + 1e-5f);
  Zin[(size_t)row * DD + tid] = (v - mean) * inv * wgt[tid] + bias[tid];
}

// ---------------- qkv ----------------
__global__ void k_qkv(const float* __restrict__ Zin, const float* __restrict__ W,
                      const float* __restrict__ bias, float* __restrict__ q,
                      float* __restrict__ k, float* __restrict__ v) {
  int row = blockIdx.x;            // b*M + t
  int b = row / MM, t = row % MM;
  int j = threadIdx.x;             // 0..383
  __shared__ float zr[128];
  if (j < 128) zr[j] = Zin[(size_t)row * DD + j];
  __syncthreads();
  float acc = bias[j];
  for (int i = 0; i < 128; i++) acc += zr[i] * W[(size_t)i * 384 + j];
  int which = j >> 7;
  int jj = j & 127;
  int hh = jj >> 4, dh = jj & 15;
  float* dst = (which == 0) ? q : (which == 1) ? k : v;
  dst[((size_t)(b * HHD + hh) * MM + t) * DHH + dh] = acc;
}

// ---------------- attention ----------------
__global__ void k_att(const float* __restrict__ q, const float* __restrict__ k,
                      const float* __restrict__ v, float* __restrict__ obuf) {
  int bh = blockIdx.x; int b = bh / HHD, hh = bh % HHD;
  __shared__ float ks[MM * DHH];
  __shared__ float vs[MM * DHH];
  const float* kp = k + (size_t)bh * MM * DHH;
  const float* vp = v + (size_t)bh * MM * DHH;
  for (int i = threadIdx.x; i < MM * DHH; i += 256) { ks[i] = kp[i]; vs[i] = vp[i]; }
  __syncthreads();
  const float scale = 0.25f;
  for (int r = threadIdx.x; r < MM; r += 256) {
    float qr[16];
    const float* qp = q + ((size_t)bh * MM + r) * DHH;
    #pragma unroll
    for (int j = 0; j < 16; j++) qr[j] = qp[j];
    float m = -1e30f, s = 0.f, o[16];
    #pragma unroll
    for (int j = 0; j < 16; j++) o[j] = 0.f;
    for (int t = 0; t < MM; t++) {
      float sc = 0.f;
      #pragma unroll
      for (int j = 0; j < 16; j++) sc += qr[j] * ks[t * 16 + j];
      sc *= scale;
      float mn = fmaxf(m, sc);
      float corr = __expf(m - mn);
      float e = __expf(sc - mn);
      s = s * corr + e;
      #pragma unroll
      for (int j = 0; j < 16; j++) o[j] = o[j] * corr + e * vs[t * 16 + j];
      m = mn;
    }
    float invs = 1.f / s;
    float* op = obuf + ((size_t)(b * MM + r)) * DD + hh * DHH;
    #pragma unroll
    for (int j = 0; j < 16; j++) op[j] = o[j] * invs;
  }
}

// ---------------- attn out proj -> Z ----------------
__global__ void k_ao(const float* __restrict__ obuf, const float* __restrict__ W,
                     const float* __restrict__ bias, float* __restrict__ Z) {
  int row = blockIdx.x; int d = threadIdx.x;
  __shared__ float orow[128];
  orow[d] = obuf[(size_t)row * DD + d];
  __syncthreads();
  float acc = bias[d];
  for (int i = 0; i < 128; i++) acc += orow[i] * W[(size_t)i * DD + d];
  Z[(size_t)row * DD + d] += acc;
}

// ---------------- Zt hi/lo [d][t-pad] ----------------
__global__ void k_zt(const float* __restrict__ Z, bf16* __restrict__ Zt_hi,
                     bf16* __restrict__ Zt_lo) {
  int dg = blockIdx.x; int b = blockIdx.y;
  int tid = threadIdx.x;
  for (int it = 0; it < 20; ++it) {
    int eid = it * 256 + tid;           // 16*320
    int d = dg * 16 + eid / TPAD; int t = eid % TPAD;
    float v = (t < MM) ? Z[((size_t)b * MM + t) * DD + d] : 0.f;
    bf16 hi, lo; split2(v, hi, lo);
    size_t idx = ((size_t)b * DD + d) * TPAD + t;
    Zt_hi[idx] = hi; Zt_lo[idx] = lo;
  }
}

// ------- deslice (MFMA, LDS-staged bases) + fused LN2 -> ln2h bf16 -------
__global__ void __launch_bounds__(256, 4)
k_deslice(const float* __restrict__ nodes, const float* __restrict__ modes,
          const bf16* __restrict__ Zt_hi, const bf16* __restrict__ Zt_lo,
          const float* __restrict__ lw, const float* __restrict__ lb,
          float* __restrict__ h, bf16* __restrict__ ln2h) {
  int xt = blockIdx.x, b = blockIdx.y;
  int x0 = xt * 64;
  int tid = threadIdx.x, w = tid >> 6, lane = tid & 63, lr = lane & 15, lg = lane >> 4;
  __shared__ float4 modes4[TPAD];   // (m0, m1, sel, mask)
  __shared__ float n0s[64], n1s[64];
  __shared__ short As_hi[64][72];   // row stride 144 B (16-mult)
  __shared__ short As_lo[64][72];
  for (int t = tid; t < TPAD; t += 256) {
    float m0 = 0.f, m1 = 0.f, sel = 0.f, mask = 0.f;
    if (t < 128)      { m0 = modes[2 * t];          m1 = modes[2 * t + 1];          mask = 1.f; }
    else if (t < 256) { m0 = modes[2 * (t - 128)];  m1 = modes[2 * (t - 128) + 1];  sel = 1.f; mask = 1.f; }
    else if (t == 256) { mask = 1.f; }              // constant-1 column
    modes4[t] = make_float4(m0, m1, sel, mask);
  }
  if (tid < 64) {
    n0s[tid] = nodes[((size_t)b * NN + x0 + tid) * 2 + 0];
    n1s[tid] = nodes[((size_t)b * NN + x0 + tid) * 2 + 1];
  }
  __syncthreads();
  const bf16* pBh = Zt_hi + ((size_t)b * DD + lr) * TPAD + lg * 8;
  const bf16* pBl = Zt_lo + ((size_t)b * DD + lr) * TPAD + lg * 8;
  f32x4 acc[8];
  #pragma unroll
  for (int i = 0; i < 8; i++) acc[i] = (f32x4){0.f, 0.f, 0.f, 0.f};
  for (int kc = 0; kc < TPAD; kc += 64) {
    __syncthreads();
    #pragma unroll
    for (int it = 0; it < 16; ++it) {
      int eid = it * 256 + tid;       // 4096 = 64 rows x 64 t
      int row = eid >> 6, tl = eid & 63;
      float4 md = modes4[kc + tl];
      float th = n0s[row] * md.x + n1s[row] * md.y;
      float s, c; __sincosf(th, &s, &c);
      float v = md.w * (c + md.z * (s - c));
      bf16 hi, lo; split2(v, hi, lo);
      As_hi[row][tl] = b2s(hi); As_lo[row][tl] = b2s(lo);
    }
    __syncthreads();
    #pragma unroll
    for (int ks2 = 0; ks2 < 2; ++ks2) {
      int ko = kc + ks2 * 32;
      bf16x8 ah = *(const bf16x8*)&As_hi[w * 16 + lr][ks2 * 32 + lg * 8];
      bf16x8 al = *(const bf16x8*)&As_lo[w * 16 + lr][ks2 * 32 + lg * 8];
      #pragma unroll
      for (int fi = 0; fi < 8; ++fi) {
        bf16x8 bh = *(const bf16x8*)(pBh + (size_t)fi * 16 * TPAD + ko);
        bf16x8 bl = *(const bf16x8*)(pBl + (size_t)fi * 16 * TPAD + ko);
        acc[fi] = __builtin_amdgcn_mfma_f32_16x16x32_bf16(ah, bh, acc[fi], 0, 0, 0);
        acc[fi] = __builtin_amdgcn_mfma_f32_16x16x32_bf16(ah, bl, acc[fi], 0, 0, 0);
        acc[fi] = __builtin_amdgcn_mfma_f32_16x16x32_bf16(al, bh, acc[fi], 0, 0, 0);
      }
    }
  }
  // epilogue: h += delta; LN2 per x-row; write h f32 + ln2h bf16
  float lwv[8], lbv[8];
  #pragma unroll
  for (int fi = 0; fi < 8; ++fi) { lwv[fi] = lw[fi * 16 + lr]; lbv[fi] = lb[fi * 16 + lr]; }
  float hv[8][4];
  float sm[4], sq[4];
  #pragma unroll
  for (int r = 0; r < 4; ++r) { sm[r] = 0.f; sq[r] = 0.f; }
  size_t rowbase = ((size_t)b * NN + x0 + w * 16 + lg * 4);
  #pragma unroll
  for (int fi = 0; fi < 8; ++fi)
    #pragma unroll
    for (int r = 0; r < 4; ++r) {
      float v = h[(rowbase + r) * DD + fi * 16 + lr] + acc[fi][r];
      hv[fi][r] = v; sm[r] += v; sq[r] += v * v;
    }
  #pragma unroll
  for (int r = 0; r < 4; ++r) {
    float s = sm[r], q = sq[r];
    s += __shfl_xor(s, 1); q += __shfl_xor(q, 1);
    s += __shfl_xor(s, 2); q += __shfl_xor(q, 2);
    s += __shfl_xor(s, 4); q += __shfl_xor(q, 4);
    s += __shfl_xor(s, 8); q += __shfl_xor(q, 8);
    float mean = s / 128.f;
    float var = q / 128.f - mean * mean;
    sm[r] = mean; sq[r] = rsqrtf(var + 1e-5f);
  }
  #pragma unroll
  for (int fi = 0; fi < 8; ++fi)
    #pragma unroll
    for (int r = 0; r < 4; ++r) {
      float v = hv[fi][r];
      h[(rowbase + r) * DD + fi * 16 + lr] = v;
      float ln = (v - sm[r]) * sq[r] * lwv[fi] + lbv[fi];
      ln2h[(rowbase + r) * DD + fi * 16 + lr] = __float2bfloat16(ln);
    }
}

// ---------------- ffnA (MFMA): mid = gelu(ln2h @ f1 + b1) bf16 ----------------
__global__ void __launch_bounds__(256, 4)
k_ffnA(const bf16* __restrict__ ln2h, const bf16* __restrict__ f1T_hi,
       const bf16* __restrict__ f1T_lo, const float* __restrict__ b1,
       bf16* __restrict__ mid) {
  int x0 = blockIdx.x * 16;
  int tid = threadIdx.x, w = tid >> 6, lane = tid & 63, lr = lane & 15, lg = lane >> 4;
  int f0 = w * 128;
  __shared__ short mid_s[16][DFFN + 8];
  const bf16* Arow = ln2h + ((size_t)x0 + lr) * DD;
  f32x4 acc[8];
  #pragma unroll
  for (int i = 0; i < 8; i++) acc[i] = (f32x4){0.f, 0.f, 0.f, 0.f};
  #pragma unroll
  for (int ks = 0; ks < 4; ++ks) {
    bf16x8 a = *(const bf16x8*)(Arow + ks * 32 + lg * 8);
    #pragma unroll
    for (int fi = 0; fi < 8; ++fi) {
      size_t widx = (size_t)(f0 + fi * 16 + lr) * DD + ks * 32 + lg * 8;
      bf16x8 bh = *(const bf16x8*)(f1T_hi + widx);
      bf16x8 bl = *(const bf16x8*)(f1T_lo + widx);
      acc[fi] = __builtin_amdgcn_mfma_f32_16x16x32_bf16(a, bh, acc[fi], 0, 0, 0);
      acc[fi] = __builtin_amdgcn_mfma_f32_16x16x32_bf16(a, bl, acc[fi], 0, 0, 0);
    }
  }
  #pragma unroll
  for (int fi = 0; fi < 8; ++fi) {
    int col = f0 + fi * 16 + lr;
    float bb = b1[col];
    #pragma unroll
    for (int r = 0; r < 4; ++r) {
      float xx = acc[fi][r] + bb;
      float gl = 0.5f * xx * (1.f + erff(xx * 0.70710678118654752f));
      mid_s[lg * 4 + r][col] = b2s(__float2bfloat16(gl));
    }
  }
  __syncthreads();
  // coalesced copy-out: 16 rows x 512 bf16 = 16 rows x 64 uint4
  #pragma unroll
  for (int it = 0; it < 4; ++it) {
    int eid = it * 256 + tid;         // 1024 = 16 rows * 64 chunks
    int row = eid >> 6, c = eid & 63;
    uint4 vv = *(const uint4*)&mid_s[row][c * 8];
    *(uint4*)(mid + ((size_t)x0 + row) * DFFN + c * 8) = vv;
  }
}

// ------- ffnB (MFMA): h += mid @ f2 + b2; write hw hi/lo -------
__global__ void __launch_bounds__(256, 4)
k_ffnB(const bf16* __restrict__ mid, const bf16* __restrict__ f2T_hi,
       const bf16* __restrict__ f2T_lo, const float* __restrict__ b2,
       const float* __restrict__ nw, float* __restrict__ h,
       bf16* __restrict__ hw_hi, bf16* __restrict__ hw_lo) {
  int x0 = blockIdx.x * 64;
  int b = x0 / NN; int xb = x0 % NN;
  int tid = threadIdx.x, w = tid >> 6, lane = tid & 63, lr = lane & 15, lg = lane >> 4;
  __shared__ float T[128][67];
  __shared__ float wls[64];
  if (tid < 64) wls[tid] = nw[(size_t)b * NN + xb + tid];
  const bf16* Arow = mid + ((size_t)x0 + w * 16 + lr) * DFFN;
  f32x4 acc[8];
  #pragma unroll
  for (int i = 0; i < 8; i++) acc[i] = (f32x4){0.f, 0.f, 0.f, 0.f};
  #pragma unroll
  for (int ks = 0; ks < 16; ++ks) {
    bf16x8 a = *(const bf16x8*)(Arow + ks * 32 + lg * 8);
    #pragma unroll
    for (int fi = 0; fi < 8; ++fi) {
      size_t widx = (size_t)(fi * 16 + lr) * DFFN + ks * 32 + lg * 8;
      bf16x8 bh = *(const bf16x8*)(f2T_hi + widx);
      bf16x8 bl = *(const bf16x8*)(f2T_lo + widx);
      acc[fi] = __builtin_amdgcn_mfma_f32_16x16x32_bf16(a, bh, acc[fi], 0, 0, 0);
      acc[fi] = __builtin_amdgcn_mfma_f32_16x16x32_bf16(a, bl, acc[fi], 0, 0, 0);
    }
  }
  size_t rowbase = (size_t)x0 + w * 16 + lg * 4;
  #pragma unroll
  for (int fi = 0; fi < 8; ++fi) {
    int d = fi * 16 + lr;
    float bb = b2[d];
    #pragma unroll
    for (int r = 0; r < 4; ++r) {
      float v = h[(rowbase + r) * DD + d] + acc[fi][r] + bb;
      h[(rowbase + r) * DD + d] = v;
      T[d][w * 16 + lg * 4 + r] = v;
    }
  }
  __syncthreads();
  for (int it = 0; it < 32; ++it) {
    int eid = it * 256 + tid; int d = eid >> 6, xl = eid & 63;
    float v = T[d][xl] * wls[xl];
    bf16 hi, lo; split2(v, hi, lo);
    size_t idx = ((size_t)b * DD + d) * NN + xb + xl;
    hw_hi[idx] = hi; hw_lo[idx] = lo;
  }
}

// ---------------- final LN + out proj (f32 out) ----------------
__global__ void k_out(const float* __restrict__ h, const float* __restrict__ lw,
                      const float* __restrict__ lb, const float* __restrict__ ow,
                      const float* __restrict__ ob, float* __restrict__ out) {
  int row = blockIdx.x; int tid = threadIdx.x;
  float v = h[(size_t)row * DD + tid];
  float s = v, q = v * v;
  for (int off = 32; off; off >>= 1) { s += __shfl_xor(s, off); q += __shfl_xor(q, off); }
  __shared__ float sh[4];
  __shared__ float sp[4];
  int wv = tid >> 6;
  if ((tid & 63) == 0) { sh[wv] = s; sh[2 + wv] = q; }
  __syncthreads();
  s = sh[0] + sh[1]; q = sh[2] + sh[3];
  float mean = s / 128.f, var = q / 128.f - mean * mean;
  float inv = rsqrtf(var + 1e-5f);
  float ln = (v - mean) * inv * lw[tid] + lb[tid];
  float p0 = ln * ow[tid * 2 + 0], p1 = ln * ow[tid * 2 + 1];
  for (int off = 32; off; off >>= 1) { p0 += __shfl_xor(p0, off); p1 += __shfl_xor(p1, off); }
  if ((tid & 63) == 0) { sp[wv] = p0; sp[2 + wv] = p1; }
  __syncthreads();
  if (tid == 0) out[(size_t)row * 2 + 0] = sp[0] + sp[1] + ob[0];
  if (tid == 1) out[(size_t)row * 2 + 1] = sp[2] + sp[3] + ob[1];
}

extern "C" void kernel_launch(void* const* d_in, const int* in_sizes, int n_in,
                              void* d_out, int out_size, void* d_ws, size_t ws_size,
                              hipStream_t stream) {
  const float* u      = (const float*)d_in[0];
  const float* nodes  = (const float*)d_in[1];
  const float* nw     = (const float*)d_in[2];
  const float* modes  = (const float*)d_in[3];
  const float* coordB = (const float*)d_in[4];
  const float* cp_w   = (const float*)d_in[5];
  const float* cp_b   = (const float*)d_in[6];
  const float* in_w   = (const float*)d_in[7];
  const float* in_b   = (const float*)d_in[8];
  const float* ln1_w  = (const float*)d_in[9];
  const float* ln1_b  = (const float*)d_in[10];
  const float* qkv_w  = (const float*)d_in[11];
  const float* qkv_b  = (const float*)d_in[12];
  const float* ao_w   = (const float*)d_in[13];
  const float* ao_b   = (const float*)d_in[14];
  const float* f1_w   = (const float*)d_in[15];
  const float* f1_b   = (const float*)d_in[16];
  const float* f2_w   = (const float*)d_in[17];
  const float* f2_b   = (const float*)d_in[18];
  const float* ln2_w  = (const float*)d_in[19];
  const float* ln2_b  = (const float*)d_in[20];
  const float* lnf_w  = (const float*)d_in[21];
  const float* lnf_b  = (const float*)d_in[22];
  const float* out_w  = (const float*)d_in[23];
  const float* out_b  = (const float*)d_in[24];

  char* ws = (char*)d_ws;
  size_t off = 0;
  bf16* bT_hi = (bf16*)(ws + off); off += (size_t)BB * TPAD * NN * 2;   // 41.9 MB
  bf16* bT_lo = (bf16*)(ws + off); off += (size_t)BB * TPAD * NN * 2;   // 41.9 MB
  float* h    = (float*)(ws + off); off += (size_t)BB * NN * DD * 4;    // 33.6 MB
  bf16* hw_hi = (bf16*)(ws + off); off += (size_t)BB * DD * NN * 2;     // 16.8 MB
  bf16* hw_lo = (bf16*)(ws + off); off += (size_t)BB * DD * NN * 2;     // 16.8 MB
  bf16* ln2h  = (bf16*)(ws + off); off += (size_t)BB * NN * DD * 2;     // 16.8 MB
  // regMid: partialT (33.6) | mid (67.1) | attention smalls @+40MB — disjoint lifetimes
  char* regMid = ws + off; off += (size_t)BB * NN * DFFN * 2;           // 67.1 MB
  float* partialT = (float*)regMid;                       // live: slice -> reduce
  bf16*  mid      = (bf16*)regMid;                        // live: ffnA -> ffnB
  float* Zin = (float*)(regMid + 40 * 1024 * 1024);       // live: ln1 -> qkv
  float* qb  = Zin + (size_t)BB * MM * DD;                // live: qkv -> att
  float* kb  = qb  + (size_t)BB * MM * DD;
  float* vb  = kb  + (size_t)BB * MM * DD;
  float* ob2 = vb  + (size_t)BB * MM * DD;                // live: att -> ao
  float* Z    = (float*)(ws + off); off += (size_t)BB * MM * DD * 4;
  bf16* Zt_hi = (bf16*)(ws + off); off += (size_t)BB * DD * TPAD * 2;
  bf16* Zt_lo = (bf16*)(ws + off); off += (size_t)BB * DD * TPAD * 2;
  bf16* f1T_hi = (bf16*)(ws + off); off += (size_t)LL * DFFN * DD * 2;
  bf16* f1T_lo = (bf16*)(ws + off); off += (size_t)LL * DFFN * DD * 2;
  bf16* f2T_hi = (bf16*)(ws + off); off += (size_t)LL * DD * DFFN * 2;
  bf16* f2T_lo = (bf16*)(ws + off); off += (size_t)LL * DD * DFFN * 2;
  // total ~239.2 MB (< 240.07 MB proven available in round 3)

  k_prepW<<<(2 * LL * DFFN * DD + 255) / 256, 256, 0, stream>>>(f1_w, f2_w, f1T_hi, f1T_lo, f2T_hi, f2T_lo);
  k_embed<<<BB * NN, 128, 0, stream>>>(u, nodes, coordB, cp_w, cp_b, in_w, in_b, h);
  k_basesT<<<dim3(NN / 256, TPAD, BB), 256, 0, stream>>>(nodes, modes, bT_hi, bT_lo);
  k_hTw<<<dim3(NN / 64, BB), 256, 0, stream>>>(h, nw, hw_hi, hw_lo);

  for (int l = 0; l < LL; l++) {
    k_slice<<<dim3(SKC, TPAD / 64, BB), 256, 0, stream>>>(bT_hi, bT_lo, hw_hi, hw_lo, partialT);
    k_reduce<<<(BB * DD * MM + 255) / 256, 256, 0, stream>>>(partialT, Z);
    k_ln1<<<BB * MM, 128, 0, stream>>>(Z, ln1_w + l * DD, ln1_b + l * DD, Zin);
    k_qkv<<<BB * MM, 384, 0, stream>>>(Zin, qkv_w + (size_t)l * DD * 3 * DD, qkv_b + l * 3 * DD, qb, kb, vb);
    k_att<<<BB * HHD, 256, 0, stream>>>(qb, kb, vb, ob2);
    k_ao<<<BB * MM, 128, 0, stream>>>(ob2, ao_w + (size_t)l * DD * DD, ao_b + l * DD, Z);
    k_zt<<<dim3(8, BB), 256, 0, stream>>>(Z, Zt_hi, Zt_lo);
    k_deslice<<<dim3(NN / 64, BB), 256, 0, stream>>>(nodes, modes, Zt_hi, Zt_lo,
                                                     ln2_w + l * DD, ln2_b + l * DD, h, ln2h);
    k_ffnA<<<BB * NN / 16, 256, 0, stream>>>(ln2h, f1T_hi + (size_t)l * DFFN * DD,
                                             f1T_lo + (size_t)l * DFFN * DD, f1_b + l * DFFN, mid);
    k_ffnB<<<BB * NN / 64, 256, 0, stream>>>(mid, f2T_hi + (size_t)l * DD * DFFN,
                                             f2T_lo + (size_t)l * DD * DFFN, f2_b + l * DD,
                                             nw, h, hw_hi, hw_lo);
  }
  k_out<<<BB * NN, 128, 0, stream>>>(h, lnf_w, lnf_b, out_w, out_b, (float*)d_out);
}